// Round 3
// baseline (908.797 us; speedup 1.0000x reference)
//
#include <hip/hip_runtime.h>
#include <stdint.h>

typedef unsigned long long u64;

#define K 27
#define S 258
#define ENC_MASK 0x7FFFFFFull         // 27 bits
#define EMPTY 0xFFFFFFFFFFFFFFFFull

// ---------- pass 1: insert packed (e<<27|enc); min-e per key ----------
// thread per (voxel, run): run = ox*3+oy, handles oz = 0..2 (3 consecutive slots)
__global__ void k_insert(const int* __restrict__ si, int N,
                         u64* __restrict__ tab, unsigned Cmask) {
    int idx = blockIdx.x * blockDim.x + threadIdx.x;
    if (idx >= N * 9) return;
    int n = idx / 9, run = idx - n * 9;
    int ox = run / 3, oy = run - ox * 3;
    int b = si[n], x = si[N + n], y = si[2 * N + n], z = si[3 * N + n];
    unsigned enc0 = (unsigned)(((b * S + x + ox) * S + (y + oy)) * S + z);
    int e0 = n * K + run * 3;
#pragma unroll
    for (int oz = 0; oz < 3; ++oz) {
        unsigned enc = enc0 + oz;
        u64 desired = ((u64)(e0 + oz) << 27) | enc;
        unsigned h = enc & Cmask;                 // locality-preserving hash
        while (true) {
            u64 cur = tab[h];                     // plain read (stale-EMPTY ok)
            if (cur == EMPTY) {
                u64 old = atomicCAS(&tab[h], EMPTY, desired);
                if (old == EMPTY) break;
                cur = old;
            }
            if ((unsigned)(cur & ENC_MASK) == enc) {
                if (desired < cur) atomicMin(&tab[h], desired);  // skip if losing
                break;
            }
            h = (h + 1) & Cmask;
        }
    }
}

// ---------- pass 2: pos_of[e], flags[e]; mark multi rows in bitmap ----------
__global__ void k_flag(const int* __restrict__ si, int N,
                       const u64* __restrict__ tab, unsigned Cmask,
                       int* __restrict__ pos_of, int* __restrict__ flags,
                       unsigned* __restrict__ multib) {
    int idx = blockIdx.x * blockDim.x + threadIdx.x;
    if (idx >= N * 9) return;
    int n = idx / 9, run = idx - n * 9;
    int ox = run / 3, oy = run - ox * 3;
    int b = si[n], x = si[N + n], y = si[2 * N + n], z = si[3 * N + n];
    unsigned enc0 = (unsigned)(((b * S + x + ox) * S + (y + oy)) * S + z);
    int e0 = n * K + run * 3;
#pragma unroll
    for (int oz = 0; oz < 3; ++oz) {
        unsigned enc = enc0 + oz;
        unsigned h = enc & Cmask;
        u64 w;
        while ((unsigned)((w = tab[h]) & ENC_MASK) != enc) h = (h + 1) & Cmask;
        int pos = (int)(w >> 27);                 // min-e of this key (22 bits)
        int e = e0 + oz;
        pos_of[e] = pos;
        int f = (pos == e) ? 1 : 0;
        flags[e] = f;
        if (!f) atomicOr(&multib[pos >> 5], 1u << (pos & 31));  // rare (~2%)
    }
}

// ---------- scan A: per-4096-tile sums ----------
__global__ void k_scanA(const int* __restrict__ flags, int* __restrict__ bsums) {
    __shared__ int s[256];
    int tid = threadIdx.x;
    const int4* f4 = (const int4*)(flags + (size_t)blockIdx.x * 4096);
    int sum = 0;
    for (int j = tid; j < 1024; j += 256) {
        int4 v = f4[j];
        sum += v.x + v.y + v.z + v.w;
    }
    s[tid] = sum; __syncthreads();
    for (int off = 128; off > 0; off >>= 1) {
        if (tid < off) s[tid] += s[tid + off];
        __syncthreads();
    }
    if (tid == 0) bsums[blockIdx.x] = s[0];
}

// ---------- scan B: exclusive scan of tile sums; total -> bsums[NB] ----------
__global__ void k_scanB(int* __restrict__ bsums, int NB) {
    __shared__ int s[1024];
    int tid = threadIdx.x;
    int v = (tid < NB) ? bsums[tid] : 0;
    s[tid] = v; __syncthreads();
    for (int off = 1; off < 1024; off <<= 1) {
        int t = (tid >= off) ? s[tid - off] : 0;
        __syncthreads();
        s[tid] += t;
        __syncthreads();
    }
    if (tid == 1023) bsums[NB] = s[1023];         // total unique count U
    if (tid < NB) bsums[tid] = s[tid] - v;        // exclusive
}

// ---------- scan C: write ranks at flag positions + out_key rows ----------
__global__ void k_scanC(int* __restrict__ r, const int* __restrict__ bsums,
                        const int* __restrict__ si, int N, int NK,
                        float* __restrict__ out_key) {
    __shared__ int s[256];
    int tid = threadIdx.x;
    int base = blockIdx.x * 4096 + tid * 16;
    int4 v0 = *(const int4*)(r + base);
    int4 v1 = *(const int4*)(r + base + 4);
    int4 v2 = *(const int4*)(r + base + 8);
    int4 v3 = *(const int4*)(r + base + 12);
    int vals[16] = {v0.x, v0.y, v0.z, v0.w, v1.x, v1.y, v1.z, v1.w,
                    v2.x, v2.y, v2.z, v2.w, v3.x, v3.y, v3.z, v3.w};
    int tsum = 0;
#pragma unroll
    for (int j = 0; j < 16; j++) tsum += vals[j];
    s[tid] = tsum; __syncthreads();
    for (int off = 1; off < 256; off <<= 1) {
        int t = (tid >= off) ? s[tid - off] : 0;
        __syncthreads();
        s[tid] += t;
        __syncthreads();
    }
    int excl = s[tid] - tsum;
    int offset = bsums[blockIdx.x] + excl;
    int run = 0;
#pragma unroll
    for (int j = 0; j < 16; j++) {
        int e = base + j;
        int rank = offset + run;
        if (vals[j] && e < NK) {
            int n = e / K; int m = e - n * K;
            int x = si[N + n], y = si[2 * N + n], z = si[3 * N + n];
            int ox = m / 9; int rm = m - ox * 9; int oy = rm / 3; int oz = rm - oy * 3;
            out_key[(size_t)rank * 3 + 0] = (float)(x + ox - 1);
            out_key[(size_t)rank * 3 + 1] = (float)(y + oy - 1);
            out_key[(size_t)rank * 3 + 2] = (float)(z + oz - 1);
            r[e] = rank;                          // rank stored only at firsts
        }
        run += vals[j];
    }
}

// ---------- zero outF rows with >1 contributor (bitmap scan) ----------
__global__ void k_zmulti(const unsigned* __restrict__ multib,
                         const int* __restrict__ r,
                         float4* __restrict__ outF4, int nwords) {
    int i = blockIdx.x * blockDim.x + threadIdx.x;
    if (i >= nwords) return;
    unsigned bits = multib[i];
    while (bits) {
        int bit = __ffs(bits) - 1; bits &= bits - 1;
        int pos = i * 32 + bit;
        int uid = r[pos];
        float4 z = {0.f, 0.f, 0.f, 0.f};
        float4* p = outF4 + (size_t)uid * 8;
#pragma unroll
        for (int j = 0; j < 8; j++) p[j] = z;
    }
}

// ---------- tail: rows >= U -> outF=0, out_key=-1 ----------
__global__ void k_tail(const int* __restrict__ bsums, int NB, int NK,
                       float* __restrict__ out_key, float4* __restrict__ outF4) {
    int U = bsums[NB];
    int rows = NK - U;
    for (int i = blockIdx.x * blockDim.x + threadIdx.x; i < rows;
         i += gridDim.x * blockDim.x) {
        int row = U + i;
        float4 z = {0.f, 0.f, 0.f, 0.f};
        float4* p = outF4 + (size_t)row * 8;
#pragma unroll
        for (int j = 0; j < 8; j++) p[j] = z;
        out_key[(size_t)row * 3 + 0] = -1.0f;
        out_key[(size_t)row * 3 + 1] = -1.0f;
        out_key[(size_t)row * 3 + 2] = -1.0f;
    }
}

// ---------- fused kernel_map write + feature scatter ----------
__global__ void k_mapscatter(const int* __restrict__ pos_of,
                             const int* __restrict__ r,
                             const unsigned* __restrict__ multib,
                             const float4* __restrict__ feat4,
                             float* __restrict__ km,
                             float* __restrict__ outF, int NK) {
    int e = blockIdx.x * blockDim.x + threadIdx.x;
    if (e >= NK) return;
    int pos = pos_of[e];
    int uid = r[pos];                             // L2/L3-hot 10.8MB array
    int multi = (multib[pos >> 5] >> (pos & 31)) & 1;
    int n = e / K; int m = e - n * K;
    km[(size_t)e * 3 + 0] = (float)n;
    km[(size_t)e * 3 + 1] = (float)uid;
    km[(size_t)e * 3 + 2] = (float)m;
    const float4* f = feat4 + (size_t)n * 8;      // reused 27x -> L1/L2-hot
    float* p = outF + (size_t)uid * 32;
    if (multi) {
#pragma unroll
        for (int g = 0; g < 8; ++g) {
            float4 v = f[g];
            atomicAdd(p + g * 4 + 0, v.x);
            atomicAdd(p + g * 4 + 1, v.y);
            atomicAdd(p + g * 4 + 2, v.z);
            atomicAdd(p + g * 4 + 3, v.w);
        }
    } else {
#pragma unroll
        for (int g = 0; g < 8; ++g) ((float4*)p)[g] = f[g];
    }
}

extern "C" void kernel_launch(void* const* d_in, const int* in_sizes, int n_in,
                              void* d_out, int out_size, void* d_ws, size_t ws_size,
                              hipStream_t stream) {
    const int* si = (const int*)d_in[0];
    const float* feat = (const float*)d_in[1];
    int N = in_sizes[0] / 4;
    int NK = N * K;                            // 2,700,000
    int NKp = (NK + 4095) & ~4095;
    int NB = NKp / 4096;                       // ~660 (<=1024)
    int nwords = (NK + 31) / 32;

    float* km = (float*)d_out;                 // [NK,3]
    float* out_key = km + (size_t)NK * 3;      // [NK,3]
    float* outF = km + (size_t)NK * 6;         // [NK,32]

    int Cbits = 23;
    size_t need = ((size_t)8 << Cbits) + (size_t)NKp * 8
                + (size_t)(nwords + NB + 2) * 4 + 64;
    if (need > ws_size) Cbits = 22;
    unsigned C = 1u << Cbits;
    unsigned Cmask = C - 1;

    char* w = (char*)d_ws;
    u64* tab         = (u64*)w; w += (size_t)C * 8;
    int* pos_of      = (int*)w; w += (size_t)NKp * 4;
    int* flags       = (int*)w; w += (size_t)NKp * 4;   // becomes ranks r
    unsigned* multib = (unsigned*)w; w += (size_t)nwords * 4;
    int* bsums       = (int*)w;

    hipMemsetAsync(tab, 0xFF, (size_t)C * 8, stream);               // EMPTY
    hipMemsetAsync(multib, 0, (size_t)nwords * 4, stream);
    if (NKp > NK) hipMemsetAsync(flags + NK, 0, (size_t)(NKp - NK) * 4, stream);

    int nb9 = (N * 9 + 255) / 256;
    int nb1 = (NK + 255) / 256;
    k_insert<<<nb9, 256, 0, stream>>>(si, N, tab, Cmask);
    k_flag<<<nb9, 256, 0, stream>>>(si, N, tab, Cmask, pos_of, flags, multib);
    k_scanA<<<NB, 256, 0, stream>>>(flags, bsums);
    k_scanB<<<1, 1024, 0, stream>>>(bsums, NB);
    k_scanC<<<NB, 256, 0, stream>>>(flags, bsums, si, N, NK, out_key);
    k_zmulti<<<(nwords + 255) / 256, 256, 0, stream>>>(multib, flags,
                                                       (float4*)outF, nwords);
    k_tail<<<512, 256, 0, stream>>>(bsums, NB, NK, out_key, (float4*)outF);
    k_mapscatter<<<nb1, 256, 0, stream>>>(pos_of, flags, multib,
                                          (const float4*)feat, km, outF, NK);
}

// Round 4
// 837.571 us; speedup vs baseline: 1.0850x; 1.0850x over previous
//
#include <hip/hip_runtime.h>
#include <stdint.h>

typedef unsigned long long u64;
typedef unsigned u32;

#define K 27
#define S 258
#define ENCMAX (4 * S * S * S)        // 68,694,048 possible keys

// ---------- pass 1: mark presence bits (one u64 atomicOr per z-run) ----------
__global__ void k_mark(const int* __restrict__ si, int N, u64* __restrict__ bits) {
    int idx = blockIdx.x * blockDim.x + threadIdx.x;
    if (idx >= N * 9) return;
    int n = idx / 9, run = idx - n * 9;
    int ox = run / 3, oy = run - ox * 3;
    int b = si[n], x = si[N + n], y = si[2 * N + n], z = si[3 * N + n];
    unsigned enc0 = (unsigned)(((b * S + x + ox) * S + (y + oy)) * S + z);
    unsigned w = enc0 >> 6; int bit = enc0 & 63;
    atomicOr(&bits[w], 7ull << bit);               // bits enc0..enc0+2 (low part)
    if (bit > 61) atomicOr(&bits[w + 1], 7ull >> (64 - bit));
}

// ---------- s1: per-4096-word tile popcount sums ----------
__global__ void s1_tilesum(const u64* __restrict__ bits, int* __restrict__ tsums) {
    __shared__ int s[256];
    int tid = threadIdx.x;
    const u64* p = bits + (size_t)blockIdx.x * 4096;
    int sum = 0;
    for (int j = tid; j < 4096; j += 256) sum += __popcll(p[j]);
    s[tid] = sum; __syncthreads();
    for (int off = 128; off > 0; off >>= 1) {
        if (tid < off) s[tid] += s[tid + off];
        __syncthreads();
    }
    if (tid == 0) tsums[blockIdx.x] = s[0];
}

// ---------- generic single-block exclusive scan (NB <= 1024); total -> a[NB] --
__global__ void k_scanB(int* __restrict__ a, int NB) {
    __shared__ int s[1024];
    int tid = threadIdx.x;
    int v = (tid < NB) ? a[tid] : 0;
    s[tid] = v; __syncthreads();
    for (int off = 1; off < 1024; off <<= 1) {
        int t = (tid >= off) ? s[tid - off] : 0;
        __syncthreads();
        s[tid] += t;
        __syncthreads();
    }
    if (tid == 1023) a[NB] = s[1023];
    if (tid < NB) a[tid] = s[tid] - v;
}

// ---------- s3: per-word exclusive popcount prefix ----------
__global__ void s3_wprefix(const u64* __restrict__ bits, const int* __restrict__ tsums,
                           u32* __restrict__ wprefix) {
    __shared__ int s[256];
    int tid = threadIdx.x;
    size_t base = (size_t)blockIdx.x * 4096 + (size_t)tid * 16;
    int pc[16]; int tsum = 0;
#pragma unroll
    for (int j = 0; j < 16; j++) { pc[j] = __popcll(bits[base + j]); tsum += pc[j]; }
    s[tid] = tsum; __syncthreads();
    for (int off = 1; off < 256; off <<= 1) {
        int t = (tid >= off) ? s[tid - off] : 0;
        __syncthreads();
        s[tid] += t;
        __syncthreads();
    }
    int run = tsums[blockIdx.x] + s[tid] - tsum;
#pragma unroll
    for (int j = 0; j < 16; j++) { wprefix[base + j] = (u32)run; run += pc[j]; }
}

// ---------- pass 2: dense key id per entry + min-e per key (L2-hot atomics) ---
__global__ void k_kid(const int* __restrict__ si, int N,
                      const u64* __restrict__ bits, const u32* __restrict__ wprefix,
                      int* __restrict__ kid, int* __restrict__ minE) {
    int idx = blockIdx.x * blockDim.x + threadIdx.x;
    if (idx >= N * 9) return;
    int n = idx / 9, run = idx - n * 9;
    int ox = run / 3, oy = run - ox * 3;
    int b = si[n], x = si[N + n], y = si[2 * N + n], z = si[3 * N + n];
    unsigned enc0 = (unsigned)(((b * S + x + ox) * S + (y + oy)) * S + z);
    int e0 = n * K + run * 3;
#pragma unroll
    for (int oz = 0; oz < 3; ++oz) {
        unsigned enc = enc0 + oz;
        unsigned w = enc >> 6; int bit = enc & 63;
        int kd = (int)wprefix[w] + __popcll(bits[w] & ((1ull << bit) - 1));
        kid[e0 + oz] = kd;
        atomicMin(&minE[kd], e0 + oz);            // fire-and-forget, cache-hot
    }
}

// ---------- pass 3 (+tile sums): flags, pos_of, multi-bitmap ----------
__global__ void k_flagA(const int* __restrict__ kid, const int* __restrict__ minE,
                        int NK, int* __restrict__ flags, int* __restrict__ pos_of,
                        u32* __restrict__ multib, int* __restrict__ bsums) {
    __shared__ int s[256];
    int tid = threadIdx.x;
    int base = blockIdx.x * 4096 + tid * 16;
    int kv[16];
    *(int4*)(kv + 0)  = *(const int4*)(kid + base + 0);
    *(int4*)(kv + 4)  = *(const int4*)(kid + base + 4);
    *(int4*)(kv + 8)  = *(const int4*)(kid + base + 8);
    *(int4*)(kv + 12) = *(const int4*)(kid + base + 12);
    int f[16], p[16]; int sum = 0;
#pragma unroll
    for (int j = 0; j < 16; j++) {
        int e = base + j;
        if (e < NK) {
            int pos = minE[kv[j]];                // L2/L3-hot gather
            p[j] = pos;
            f[j] = (pos == e) ? 1 : 0;
            if (!f[j]) atomicOr(&multib[pos >> 5], 1u << (pos & 31));
        } else { p[j] = 0; f[j] = 0; }
        sum += f[j];
    }
#pragma unroll
    for (int q = 0; q < 4; q++) {
        *(int4*)(flags + base + q * 4)  = *(int4*)(f + q * 4);
        *(int4*)(pos_of + base + q * 4) = *(int4*)(p + q * 4);
    }
    s[tid] = sum; __syncthreads();
    for (int off = 128; off > 0; off >>= 1) {
        if (tid < off) s[tid] += s[tid + off];
        __syncthreads();
    }
    if (tid == 0) bsums[blockIdx.x] = s[0];
}

// ---------- scan C: ranks at firsts + out_key rows ----------
__global__ void k_scanC(int* __restrict__ r, const int* __restrict__ bsums,
                        const int* __restrict__ si, int N, int NK,
                        float* __restrict__ out_key) {
    __shared__ int s[256];
    int tid = threadIdx.x;
    int base = blockIdx.x * 4096 + tid * 16;
    int vals[16];
    *(int4*)(vals + 0)  = *(const int4*)(r + base + 0);
    *(int4*)(vals + 4)  = *(const int4*)(r + base + 4);
    *(int4*)(vals + 8)  = *(const int4*)(r + base + 8);
    *(int4*)(vals + 12) = *(const int4*)(r + base + 12);
    int tsum = 0;
#pragma unroll
    for (int j = 0; j < 16; j++) tsum += vals[j];
    s[tid] = tsum; __syncthreads();
    for (int off = 1; off < 256; off <<= 1) {
        int t = (tid >= off) ? s[tid - off] : 0;
        __syncthreads();
        s[tid] += t;
        __syncthreads();
    }
    int offset = bsums[blockIdx.x] + s[tid] - tsum;
    int run = 0;
#pragma unroll
    for (int j = 0; j < 16; j++) {
        int e = base + j;
        int rank = offset + run;
        if (vals[j] && e < NK) {
            int n = e / K; int m = e - n * K;
            int x = si[N + n], y = si[2 * N + n], z = si[3 * N + n];
            int ox = m / 9; int rm = m - ox * 9; int oy = rm / 3; int oz = rm - oy * 3;
            out_key[(size_t)rank * 3 + 0] = (float)(x + ox - 1);
            out_key[(size_t)rank * 3 + 1] = (float)(y + oy - 1);
            out_key[(size_t)rank * 3 + 2] = (float)(z + oz - 1);
            r[e] = rank;
        }
        run += vals[j];
    }
}

// ---------- zero outF rows with >1 contributor ----------
__global__ void k_zmulti(const u32* __restrict__ multib, const int* __restrict__ r,
                         float4* __restrict__ outF4, int nwords) {
    int i = blockIdx.x * blockDim.x + threadIdx.x;
    if (i >= nwords) return;
    u32 bits = multib[i];
    while (bits) {
        int bit = __ffs(bits) - 1; bits &= bits - 1;
        int uid = r[i * 32 + bit];
        float4 z = {0.f, 0.f, 0.f, 0.f};
        float4* p = outF4 + (size_t)uid * 8;
#pragma unroll
        for (int j = 0; j < 8; j++) p[j] = z;
    }
}

// ---------- tail: rows >= U -> outF=0, out_key=-1 ----------
__global__ void k_tail(const int* __restrict__ bsums, int NB, int NK,
                       float* __restrict__ out_key, float4* __restrict__ outF4) {
    int U = bsums[NB];
    int rows = NK - U;
    for (int i = blockIdx.x * blockDim.x + threadIdx.x; i < rows;
         i += gridDim.x * blockDim.x) {
        int row = U + i;
        float4 z = {0.f, 0.f, 0.f, 0.f};
        float4* p = outF4 + (size_t)row * 8;
#pragma unroll
        for (int j = 0; j < 8; j++) p[j] = z;
        out_key[(size_t)row * 3 + 0] = -1.0f;
        out_key[(size_t)row * 3 + 1] = -1.0f;
        out_key[(size_t)row * 3 + 2] = -1.0f;
    }
}

// ---------- fused kernel_map write + feature scatter ----------
__global__ void k_mapscatter(const int* __restrict__ pos_of, const int* __restrict__ r,
                             const u32* __restrict__ multib,
                             const float4* __restrict__ feat4,
                             float* __restrict__ km, float* __restrict__ outF, int NK) {
    int e = blockIdx.x * blockDim.x + threadIdx.x;
    if (e >= NK) return;
    int pos = pos_of[e];
    int uid = r[pos];                             // pos==e for ~97% -> seq read
    int multi = (multib[pos >> 5] >> (pos & 31)) & 1;
    int n = e / K; int m = e - n * K;
    km[(size_t)e * 3 + 0] = (float)n;
    km[(size_t)e * 3 + 1] = (float)uid;
    km[(size_t)e * 3 + 2] = (float)m;
    const float4* f = feat4 + (size_t)n * 8;      // reused 27x -> L1/L2-hot
    float* p = outF + (size_t)uid * 32;
    if (multi) {
#pragma unroll
        for (int g = 0; g < 8; ++g) {
            float4 v = f[g];
            atomicAdd(p + g * 4 + 0, v.x);
            atomicAdd(p + g * 4 + 1, v.y);
            atomicAdd(p + g * 4 + 2, v.z);
            atomicAdd(p + g * 4 + 3, v.w);
        }
    } else {
#pragma unroll
        for (int g = 0; g < 8; ++g) ((float4*)p)[g] = f[g];  // uid monotone -> seq
    }
}

extern "C" void kernel_launch(void* const* d_in, const int* in_sizes, int n_in,
                              void* d_out, int out_size, void* d_ws, size_t ws_size,
                              hipStream_t stream) {
    const int* si = (const int*)d_in[0];
    const float* feat = (const float*)d_in[1];
    int N = in_sizes[0] / 4;
    int NK = N * K;                            // 2,700,000
    int NKp = (NK + 4095) & ~4095;
    int NB = NKp / 4096;                       // ~660 (<=1024)
    int nwords = (NK + 31) / 32;

    int NW = (ENCMAX + 63) / 64;               // 1,073,345 bitmap words
    int NT = (NW + 4095) / 4096;               // 263 tiles (<=1024)
    int NWp = NT * 4096;

    float* km = (float*)d_out;                 // [NK,3]
    float* out_key = km + (size_t)NK * 3;      // [NK,3]
    float* outF = km + (size_t)NK * 6;         // [NK,32]

    char* w = (char*)d_ws;
    u64* bits    = (u64*)w; w += (size_t)NWp * 8;       // 8.6 MB
    u32* wprefix = (u32*)w; w += (size_t)NWp * 4;       // 4.3 MB
    int* tsums   = (int*)w; w += (size_t)(NT + 1) * 4;
    int* minE    = (int*)w; w += (size_t)NK * 4;        // 10.8 MB
    int* kid     = (int*)w; w += (size_t)NKp * 4;
    int* flags   = (int*)w; w += (size_t)NKp * 4;       // becomes ranks r
    int* pos_of  = (int*)w; w += (size_t)NKp * 4;
    u32* multib  = (u32*)w; w += (size_t)nwords * 4;
    int* bsums   = (int*)w;

    hipMemsetAsync(bits, 0, (size_t)NWp * 8, stream);
    hipMemsetAsync(minE, 0x7F, (size_t)NK * 4, stream);   // +INF-ish for atomicMin
    hipMemsetAsync(multib, 0, (size_t)nwords * 4, stream);

    int nb9 = (N * 9 + 255) / 256;
    int nb1 = (NK + 255) / 256;
    k_mark<<<nb9, 256, 0, stream>>>(si, N, bits);
    s1_tilesum<<<NT, 256, 0, stream>>>(bits, tsums);
    k_scanB<<<1, 1024, 0, stream>>>(tsums, NT);
    s3_wprefix<<<NT, 256, 0, stream>>>(bits, tsums, wprefix);
    k_kid<<<nb9, 256, 0, stream>>>(si, N, bits, wprefix, kid, minE);
    k_flagA<<<NB, 256, 0, stream>>>(kid, minE, NK, flags, pos_of, multib, bsums);
    k_scanB<<<1, 1024, 0, stream>>>(bsums, NB);
    k_scanC<<<NB, 256, 0, stream>>>(flags, bsums, si, N, NK, out_key);
    k_zmulti<<<(nwords + 255) / 256, 256, 0, stream>>>(multib, flags,
                                                       (float4*)outF, nwords);
    k_tail<<<512, 256, 0, stream>>>(bsums, NB, NK, out_key, (float4*)outF);
    k_mapscatter<<<nb1, 256, 0, stream>>>(pos_of, flags, multib,
                                          (const float4*)feat, km, outF, NK);
}